// Round 1
// baseline (417.203 us; speedup 1.0000x reference)
//
#include <hip/hip_runtime.h>
#include <math.h>

#define B_    128
#define T_    24
#define NN    300
#define EE    9000
#define GG    (B_ * T_)
#define GRUH  12
#define OUTF  1200

// ---------------------------------------------------------------------------
// Kernel 1: build CSR of edges grouped by dst (topology shared by all graphs)
// ws layout: row_ptr[NN+1], csr_src[EE], csr_eid[EE]
// ---------------------------------------------------------------------------
__global__ __launch_bounds__(1024) void build_csr(
    const int* __restrict__ src, const int* __restrict__ dst,
    int* __restrict__ row_ptr, int* __restrict__ csr_src, int* __restrict__ csr_eid)
{
    __shared__ int cnt[512];
    __shared__ int bufA[512], bufB[512];
    __shared__ int offs[NN];
    const int tid = threadIdx.x;

    for (int i = tid; i < 512; i += 1024) cnt[i] = 0;
    __syncthreads();
    for (int e = tid; e < EE; e += 1024) atomicAdd(&cnt[dst[e]], 1);
    __syncthreads();

    // Hillis-Steele inclusive scan over 512 (padded) elements
    int* cur = bufA; int* nxt = bufB;
    if (tid < 512) cur[tid] = cnt[tid];
    __syncthreads();
    for (int d = 1; d < 512; d <<= 1) {
        if (tid < 512) nxt[tid] = cur[tid] + (tid >= d ? cur[tid - d] : 0);
        __syncthreads();
        int* t = cur; cur = nxt; nxt = t;
    }
    // exclusive prefix -> row_ptr / offsets
    if (tid <= NN) row_ptr[tid] = (tid == 0) ? 0 : cur[tid - 1];
    if (tid < NN)  offs[tid]    = (tid == 0) ? 0 : cur[tid - 1];
    __syncthreads();

    for (int e = tid; e < EE; e += 1024) {
        int d = dst[e];
        int pos = atomicAdd(&offs[d], 1);
        csr_src[pos] = src[e];
        csr_eid[pos] = e;
    }
}

// ---------------------------------------------------------------------------
// Kernel 2: per-graph EdgeGAT + mean pool, collapsed to scalar S[g]
//   S[g] = sum_n ( sum_{e in dst==n} softmax(e) * x[src_e] )
// pass 1 (edge-parallel, coalesced): logits v_e -> LDS
// pass 2 (node-parallel, atomic-free): per-node max / exp-sum / weighted sum
// ---------------------------------------------------------------------------
__global__ __launch_bounds__(320) void gat_pool(
    const float* __restrict__ x, const float* __restrict__ ew,
    const int* __restrict__ src, const int* __restrict__ dst,
    const float* __restrict__ w_node, const float* __restrict__ w_edge,
    const float* __restrict__ attn_l, const float* __restrict__ attn_r,
    const float* __restrict__ attn_e,
    const int* __restrict__ row_ptr, const int* __restrict__ csr_src,
    const int* __restrict__ csr_eid,
    float* __restrict__ S)
{
    __shared__ float xs[NN];
    __shared__ float evals[EE];
    __shared__ float red[5];

    const int g = blockIdx.x;
    const int tid = threadIdx.x;

    // scalar attention constants (tiny, L2-broadcast)
    float cL = 0.f, cR = 0.f, cE = 0.f;
#pragma unroll
    for (int o = 0; o < 4; o++) {
        float wn = w_node[o];
        cL += wn * attn_l[o];
        cR += wn * attn_r[o];
        cE += w_edge[o] * attn_e[o];
    }

    const float* xrow = x + (size_t)g * NN;
    const float* erow = ew + (size_t)g * EE;

    for (int i = tid; i < NN; i += 320) xs[i] = xrow[i];
    __syncthreads();

    // pass 1: coalesced ew read, leaky-relu logits into LDS
    for (int e = tid; e < EE; e += 320) {
        float v = cL * xs[src[e]] + cR * xs[dst[e]] + cE * erow[e];
        v = (v >= 0.f) ? v : 0.2f * v;
        evals[e] = v;
    }
    __syncthreads();

    // pass 2: one thread per dst node, no atomics
    float acc = 0.f;
    if (tid < NN) {
        const int beg = row_ptr[tid];
        const int end = row_ptr[tid + 1];
        float m = -3.402823466e38f;
        for (int i = beg; i < end; i++) m = fmaxf(m, evals[csr_eid[i]]);
        float den = 0.f, num = 0.f;
        for (int i = beg; i < end; i++) {
            float exv = __expf(evals[csr_eid[i]] - m);
            den += exv;
            num += exv * xs[csr_src[i]];
        }
        if (end > beg) acc = num / den;
    }

    // block reduce (5 waves)
    for (int off = 32; off > 0; off >>= 1) acc += __shfl_down(acc, off);
    if ((tid & 63) == 0) red[tid >> 6] = acc;
    __syncthreads();
    if (tid == 0) S[g] = red[0] + red[1] + red[2] + red[3] + red[4];
}

// ---------------------------------------------------------------------------
// Kernel 3: GRU (24 steps, hidden 12) + FC (12 -> 1200). One wave per batch.
// pooled[b,t,o] = (S[g]/N) * w_node[o] + gat_bias[o]
// ---------------------------------------------------------------------------
__device__ __forceinline__ float sigmoidf_(float v) { return 1.0f / (1.0f + __expf(-v)); }

__global__ __launch_bounds__(64) void gru_fc(
    const float* __restrict__ S,
    const float* __restrict__ w_node, const float* __restrict__ gat_bias,
    const float* __restrict__ w_ih, const float* __restrict__ w_hh,
    const float* __restrict__ b_ih, const float* __restrict__ b_hh,
    const float* __restrict__ fc_w, const float* __restrict__ fc_b,
    float* __restrict__ out)
{
    __shared__ float h[GRUH];
    __shared__ float gi_s[36], gh_s[36];

    const int b = blockIdx.x;
    const int lane = threadIdx.x;

    float wn[4], gb[4];
#pragma unroll
    for (int i = 0; i < 4; i++) {
        wn[i] = w_node[i] * (1.0f / (float)NN);
        gb[i] = gat_bias[i];
    }

    float wih[4], whh[12], bih = 0.f, bhh = 0.f;
    if (lane < 36) {
#pragma unroll
        for (int i = 0; i < 4; i++)  wih[i] = w_ih[lane * 4 + i];
#pragma unroll
        for (int j = 0; j < 12; j++) whh[j] = w_hh[lane * 12 + j];
        bih = b_ih[lane];
        bhh = b_hh[lane];
    }
    if (lane < GRUH) h[lane] = 0.f;
    __syncthreads();

    for (int t = 0; t < T_; t++) {
        const float Sg = S[b * T_ + t];
        if (lane < 36) {
            float gi = bih, gh = bhh;
#pragma unroll
            for (int i = 0; i < 4; i++)  gi += (Sg * wn[i] + gb[i]) * wih[i];
#pragma unroll
            for (int j = 0; j < 12; j++) gh += h[j] * whh[j];
            gi_s[lane] = gi;
            gh_s[lane] = gh;
        }
        __syncthreads();
        if (lane < GRUH) {
            float r = sigmoidf_(gi_s[lane] + gh_s[lane]);
            float z = sigmoidf_(gi_s[12 + lane] + gh_s[12 + lane]);
            float n = tanhf(gi_s[24 + lane] + r * gh_s[24 + lane]);
            h[lane] = (1.f - z) * n + z * h[lane];
        }
        __syncthreads();
    }

    // FC epilogue: 1200 outputs per batch across 64 lanes
    for (int j = lane; j < OUTF; j += 64) {
        float o = fc_b[j];
#pragma unroll
        for (int k = 0; k < GRUH; k++) o += h[k] * fc_w[j * GRUH + k];
        out[(size_t)b * OUTF + j] = o;
    }
}

// ---------------------------------------------------------------------------
extern "C" void kernel_launch(void* const* d_in, const int* in_sizes, int n_in,
                              void* d_out, int out_size, void* d_ws, size_t ws_size,
                              hipStream_t stream)
{
    const float* x        = (const float*)d_in[0];
    const float* ew       = (const float*)d_in[1];
    const int*   src      = (const int*)d_in[2];
    const int*   dst      = (const int*)d_in[3];
    const float* w_node   = (const float*)d_in[4];
    const float* w_edge   = (const float*)d_in[5];
    const float* attn_l   = (const float*)d_in[6];
    const float* attn_r   = (const float*)d_in[7];
    const float* attn_e   = (const float*)d_in[8];
    const float* gat_bias = (const float*)d_in[9];
    const float* w_ih     = (const float*)d_in[10];
    const float* w_hh     = (const float*)d_in[11];
    const float* b_ih     = (const float*)d_in[12];
    const float* b_hh     = (const float*)d_in[13];
    const float* fc_w     = (const float*)d_in[14];
    const float* fc_b     = (const float*)d_in[15];
    float* out = (float*)d_out;

    // workspace layout
    char* ws = (char*)d_ws;
    float* S       = (float*)ws;                       // GG floats
    int*   row_ptr = (int*)(ws + GG * sizeof(float));  // NN+1 (pad to 304)
    int*   csr_src = row_ptr + 304;                    // EE
    int*   csr_eid = csr_src + EE;                     // EE

    build_csr<<<1, 1024, 0, stream>>>(src, dst, row_ptr, csr_src, csr_eid);
    gat_pool<<<GG, 320, 0, stream>>>(x, ew, src, dst, w_node, w_edge,
                                     attn_l, attn_r, attn_e,
                                     row_ptr, csr_src, csr_eid, S);
    gru_fc<<<B_, 64, 0, stream>>>(S, w_node, gat_bias, w_ih, w_hh,
                                  b_ih, b_hh, fc_w, fc_b, out);
}